// Round 8
// baseline (2249.025 us; speedup 1.0000x reference)
//
#include <hip/hip_runtime.h>

static constexpr int B_    = 64;
static constexpr int N_    = 2048;
static constexpr int DI_   = 8;
static constexpr int O_    = 32;
static constexpr int P_    = 16;
static constexpr int OP_   = O_ * P_;      // 512
static constexpr int M_    = OP_ * B_;     // 32768 s elements
static constexpr int WROW_ = P_ * DI_;     // 128 floats per (n,o) row
static constexpr int WN_   = O_ * WROW_;   // 4096 floats per n (16 KB)
static constexpr int CHUNK_ = 4;
static constexpr int NBLK_  = N_ / CHUNK_; // 512

// MODE 0: iter0 (uniform rw; 1/32 folded into v_kernel). No softmax, no v.
// MODE 1: per nn: phase A (logits->exp->LDS, preds NOT kept) | bar | phase B
//         (recompute preds from LDS-resident W, fold rw). W via LDS broadcast.
// MODE 2: MODE1 + normalized rw rows to rw_out (v_in = v0+v1 by linearity).
// Register hygiene: no address-of on privates; constant indices only.
// W is staged to LDS with vector loads and read wave-uniform (ds broadcast) --
// this takes the scalar-cache (s_load) path out of the loop entirely (the
// R4/R6/R7 wall: 64-95us at VALUBusy 12-27% regardless of FLOPs).
template <int MODE, bool ATOMIC>
__global__ __launch_bounds__(1024, 4)
void fused_pass(const float* __restrict__ x, const float* __restrict__ W,
                const float* __restrict__ v_in, float* __restrict__ s_out,
                float* __restrict__ rw_out) {
  __shared__ float Wl[2][WN_];               // 2 x 16 KB double-buffered W[n]
  __shared__ float x_lds[CHUNK_ * 8 * 65];   // [rem=(nn*8+i)][b] pad 65 (8.3 KB)
  __shared__ float e_lds[O_ * B_];           // exp storage (8 KB)
  const int tid  = threadIdx.x;
  const int lane = tid & 63;                 // lane == batch b
  const int wave = tid >> 6;                 // 0..15; wave owns o = 2w, 2w+1
  const int n0   = blockIdx.x * CHUNK_;
  const float4* Wg4 = (const float4*)W;      // W[n] = 1024 float4

  // prologue: stage W[n0] + x, one barrier
  float4 w0 = Wg4[(size_t)n0 * 1024 + tid];
  #pragma unroll
  for (int k = 0; k < 2; ++k) {
    int d = k * 1024 + tid;
    int b = d >> 5, rem = d & 31;
    x_lds[rem * 65 + b] = x[b * (N_ * DI_) + n0 * DI_ + rem];
  }
  ((float4*)&Wl[0][0])[tid] = w0;

  float s_r[32];
  #pragma unroll
  for (int q = 0; q < 32; ++q) s_r[q] = 0.0f;

  __syncthreads();

  #pragma unroll 1
  for (int nn = 0; nn < CHUNK_; ++nn) {
    const int n   = n0 + nn;
    const int cur = nn & 1;
    float4 wpre;
    if (nn < CHUNK_ - 1) wpre = Wg4[(size_t)(n + 1) * 1024 + tid];  // prefetch

    float xr[8];
    #pragma unroll
    for (int i = 0; i < 8; ++i) xr[i] = x_lds[(nn * 8 + i) * 65 + lane];

    if (MODE != 0) {
      float e0 = 0.0f, e1 = 0.0f;
      // ---- phase A: logits -> exp -> LDS (preds recomputed later, not kept)
      #pragma unroll
      for (int oo = 0; oo < 2; ++oo) {
        const int o = wave * 2 + oo;
        const float4* wls = (const float4*)&Wl[cur][o * WROW_];  // wave-uniform
        const float4* vp  = (const float4*)(v_in + (size_t)lane * OP_ + o * P_);
        float acc = 0.0f;
        #pragma unroll
        for (int q = 0; q < 4; ++q) {
          const float4 vq = vp[q];
          #pragma unroll
          for (int pp = 0; pp < 4; ++pp) {
            const int p = q * 4 + pp;
            const float4 wa = wls[p * 2];
            const float4 wb = wls[p * 2 + 1];
            float pv = wa.x * xr[0];
            pv = __builtin_fmaf(wa.y, xr[1], pv);
            pv = __builtin_fmaf(wa.z, xr[2], pv);
            pv = __builtin_fmaf(wa.w, xr[3], pv);
            pv = __builtin_fmaf(wb.x, xr[4], pv);
            pv = __builtin_fmaf(wb.y, xr[5], pv);
            pv = __builtin_fmaf(wb.z, xr[6], pv);
            pv = __builtin_fmaf(wb.w, xr[7], pv);
            const float vc = (pp == 0) ? vq.x : (pp == 1) ? vq.y
                           : (pp == 2) ? vq.z : vq.w;
            acc = __builtin_fmaf(pv, vc, acc);
          }
        }
        // no-max softmax: |logit| small analytically; exp safe in fp32
        const float e = __expf(acc);
        if (oo == 0) e0 = e; else e1 = e;
        if (MODE == 2) e_lds[o * B_ + lane] = e;       // individual (rw output)
      }
      if (MODE == 1) e_lds[wave * B_ + lane] = e0 + e1;  // pair partial
      __syncthreads();  // A complete

      // ---- phase B: Z, then s += (e/Z) * preds (recompute from LDS W) ----
      float Z = 0.0f;
      if (MODE == 1) {
        #pragma unroll
        for (int w = 0; w < 16; ++w) Z += e_lds[w * B_ + lane];
      } else {
        #pragma unroll
        for (int o = 0; o < O_; ++o) Z += e_lds[o * B_ + lane];
      }
      const float rZ = __builtin_amdgcn_rcpf(Z);

      #pragma unroll
      for (int oo = 0; oo < 2; ++oo) {
        const int o = wave * 2 + oo;
        const float rw = ((oo == 0) ? e0 : e1) * rZ;
        const float4* wls = (const float4*)&Wl[cur][o * WROW_];
        #pragma unroll
        for (int q = 0; q < 4; ++q) {
          #pragma unroll
          for (int pp = 0; pp < 4; ++pp) {
            const int p = q * 4 + pp;
            const float4 wa = wls[p * 2];
            const float4 wb = wls[p * 2 + 1];
            float pv = wa.x * xr[0];
            pv = __builtin_fmaf(wa.y, xr[1], pv);
            pv = __builtin_fmaf(wa.z, xr[2], pv);
            pv = __builtin_fmaf(wa.w, xr[3], pv);
            pv = __builtin_fmaf(wb.x, xr[4], pv);
            pv = __builtin_fmaf(wb.y, xr[5], pv);
            pv = __builtin_fmaf(wb.z, xr[6], pv);
            pv = __builtin_fmaf(wb.w, xr[7], pv);
            s_r[oo * 16 + p] = __builtin_fmaf(rw, pv, s_r[oo * 16 + p]);
          }
        }
      }

      if (MODE == 2 && wave == nn) {
        float* rp = rw_out + ((size_t)lane * N_ + n) * O_;
        #pragma unroll
        for (int o4 = 0; o4 < 8; ++o4) {
          float4 t;
          t.x = e_lds[(o4 * 4 + 0) * B_ + lane] * rZ;
          t.y = e_lds[(o4 * 4 + 1) * B_ + lane] * rZ;
          t.z = e_lds[(o4 * 4 + 2) * B_ + lane] * rZ;
          t.w = e_lds[(o4 * 4 + 3) * B_ + lane] * rZ;
          ((float4*)rp)[o4] = t;
        }
      }
    } else {
      // ---- MODE0: uniform rw (scale folded downstream) ----
      #pragma unroll
      for (int oo = 0; oo < 2; ++oo) {
        const int o = wave * 2 + oo;
        const float4* wls = (const float4*)&Wl[cur][o * WROW_];
        #pragma unroll
        for (int q = 0; q < 4; ++q) {
          #pragma unroll
          for (int pp = 0; pp < 4; ++pp) {
            const int p = q * 4 + pp;
            const float4 wa = wls[p * 2];
            const float4 wb = wls[p * 2 + 1];
            float pv = wa.x * xr[0];
            pv = __builtin_fmaf(wa.y, xr[1], pv);
            pv = __builtin_fmaf(wa.z, xr[2], pv);
            pv = __builtin_fmaf(wa.w, xr[3], pv);
            pv = __builtin_fmaf(wb.x, xr[4], pv);
            pv = __builtin_fmaf(wb.y, xr[5], pv);
            pv = __builtin_fmaf(wb.z, xr[6], pv);
            pv = __builtin_fmaf(wb.w, xr[7], pv);
            s_r[oo * 16 + p] += pv;
          }
        }
      }
    }

    if (nn < CHUNK_ - 1) ((float4*)&Wl[cur ^ 1][0])[tid] = wpre;  // stage next W
    __syncthreads();  // next-W visible; e_lds/Wl[cur] free for reuse
  }

  // epilogue: block partial (layout [blk][q=o*16+p][b]) or atomic fallback
  if (ATOMIC) {
    #pragma unroll
    for (int oo = 0; oo < 2; ++oo) {
      float* sp = s_out + (size_t)((wave * 2 + oo) * P_) * B_ + lane;
      #pragma unroll
      for (int p = 0; p < P_; ++p) atomicAdd(&sp[p * B_], s_r[oo * 16 + p]);
    }
  } else {
    #pragma unroll
    for (int oo = 0; oo < 2; ++oo) {
      float* sp = s_out + (size_t)blockIdx.x * M_ +
                  (size_t)((wave * 2 + oo) * P_) * B_ + lane;
      #pragma unroll
      for (int p = 0; p < P_; ++p) sp[p * B_] = s_r[oo * 16 + p];
    }
  }
}

// stage-1 reduction: P[K][M_] -> P2[16][M_]; grid 16 groups x 16 m-chunks.
__global__ __launch_bounds__(1024)
void reduce1(const float* __restrict__ spart, float* __restrict__ p2, int K) {
  const int g  = blockIdx.x >> 4;
  const int mc = blockIdx.x & 15;
  const int kpg = K >> 4;
  const int m0 = mc * 2048 + threadIdx.x;
  float a0 = 0.0f, a1 = 0.0f;
  const float* p = spart + (size_t)(g * kpg) * M_;
  for (int k = 0; k < kpg; ++k) {
    a0 += p[(size_t)k * M_ + m0];
    a1 += p[(size_t)k * M_ + m0 + 1024];
  }
  p2[(size_t)g * M_ + m0]        = a0;
  p2[(size_t)g * M_ + m0 + 1024] = a1;
}

// sum ngroups (stride M_) + squash; optionally add v_add; optionally zero a buffer.
__global__ __launch_bounds__(1024)
void v_kernel(const float* __restrict__ src, int ngroups, float scale,
              const float* __restrict__ v_add, float* __restrict__ v_out,
              float* __restrict__ zero_buf) {
  __shared__ float sq[P_ * 64];
  const int t = threadIdx.x;
  const int b = t & 63;
  const int p = t >> 6;
  const int o = blockIdx.x;
  const int q = o * P_ + p;
  float acc = 0.0f;
  for (int g = 0; g < ngroups; ++g) acc += src[(size_t)g * M_ + q * 64 + b];
  acc *= scale;
  sq[p * 64 + b] = acc * acc;
  if (zero_buf) zero_buf[blockIdx.x * 1024 + t] = 0.0f;
  __syncthreads();
  float s2 = 0.0f;
  #pragma unroll
  for (int pp = 0; pp < P_; ++pp) s2 += sq[pp * 64 + b];
  float sc = (s2 / (1.0f + s2)) / sqrtf(s2 + 1e-7f);
  float v = acc * sc;
  const int idx = b * OP_ + q;   // v layout [b][o][p]
  v_out[idx] = v + (v_add ? v_add[idx] : 0.0f);
}

extern "C" void kernel_launch(void* const* d_in, const int* in_sizes, int n_in,
                              void* d_out, int out_size, void* d_ws, size_t ws_size,
                              hipStream_t stream) {
  (void)in_sizes; (void)n_in; (void)out_size;
  const float* x = (const float*)d_in[0];
  const float* W = (const float*)d_in[1];
  float* out_v  = (float*)d_out;                       // [64][32][16]
  float* out_rw = out_v + (size_t)B_ * O_ * P_;        // [64][2048][32]
  float* vws   = (float*)d_ws;                         // v0
  float* vsum  = vws + M_;                             // v0+v1
  float* p2    = vsum + M_;                            // 16 * M_
  float* spart = p2 + 16 * M_;                         // NBLK_ * M_

  const size_t need = (size_t)(2 * M_ + 16 * M_ + (size_t)NBLK_ * M_) * 4;

  dim3 gF(NBLK_), bF(1024), gV(O_), bV(1024), gR(256);
  if (ws_size >= need) {
    fused_pass<0, false><<<gF, bF, 0, stream>>>(x, W, nullptr, spart, nullptr);
    reduce1<<<gR, bF, 0, stream>>>(spart, p2, NBLK_);
    v_kernel<<<gV, bV, 0, stream>>>(p2, 16, 1.0f / 32.0f, nullptr, vws, nullptr);
    fused_pass<1, false><<<gF, bF, 0, stream>>>(x, W, vws, spart, nullptr);
    reduce1<<<gR, bF, 0, stream>>>(spart, p2, NBLK_);
    v_kernel<<<gV, bV, 0, stream>>>(p2, 16, 1.0f, vws, vsum, nullptr);
    fused_pass<2, false><<<gF, bF, 0, stream>>>(x, W, vsum, spart, out_rw);
    reduce1<<<gR, bF, 0, stream>>>(spart, p2, NBLK_);
    v_kernel<<<gV, bV, 0, stream>>>(p2, 16, 1.0f, nullptr, out_v, nullptr);
  } else {
    // atomic fallback for small ws
    float* sAb = p2;
    float* sBb = sAb + M_;
    hipMemsetAsync(sAb, 0, (size_t)M_ * sizeof(float), stream);
    fused_pass<0, true><<<gF, bF, 0, stream>>>(x, W, nullptr, sAb, nullptr);
    v_kernel<<<gV, bV, 0, stream>>>(sAb, 1, 1.0f / 32.0f, nullptr, vws, sBb);
    fused_pass<1, true><<<gF, bF, 0, stream>>>(x, W, vws, sBb, nullptr);
    v_kernel<<<gV, bV, 0, stream>>>(sBb, 1, 1.0f, vws, vsum, sAb);
    fused_pass<2, true><<<gF, bF, 0, stream>>>(x, W, vsum, sAb, out_rw);
    v_kernel<<<gV, bV, 0, stream>>>(sAb, 1, 1.0f, nullptr, out_v, nullptr);
  }
}

// Round 9
// 791.683 us; speedup vs baseline: 2.8408x; 2.8408x over previous
//
#include <hip/hip_runtime.h>

static constexpr int B_    = 64;
static constexpr int N_    = 2048;
static constexpr int DI_   = 8;
static constexpr int O_    = 32;
static constexpr int P_    = 16;
static constexpr int OP_   = O_ * P_;      // 512
static constexpr int M_    = OP_ * B_;     // 32768 s elements
static constexpr int WROW_ = P_ * DI_;     // 128 floats per (n,o) row
static constexpr int WN_   = O_ * WROW_;   // 4096 floats per n (16 KB)
static constexpr int CHUNK_ = 8;
static constexpr int NBLK_  = N_ / CHUNK_; // 256

// MODE 0: iter0 (uniform rw; 1/32 folded into v_kernel). No softmax, no v.
// MODE 1: merged per nn: preds in regs (pr[2][16]) + logits -> exp -> LDS,
//         one Z-reduction, fold rw*pr. W via LDS broadcast (vector path).
// MODE 2: MODE1 + normalized rw rows to rw_out (v_in = v0+v1 by linearity).
//
// LESSONS ENCODED:
//  - __launch_bounds__ 2nd arg = minBlocksPerCU (CUDA semantics). (1024,4)
//    forced a 64-VGPR cap -> spill -> GB-scale scratch traffic (R5/R7/R8).
//    Use (1024,1) so the allocator can take ~100 VGPRs.
//  - No address-of on private arrays; constant indices only (alloca killer).
//  - W must NOT go through the scalar (s_load) path: 16 waves thrash the
//    scalar cache -> 64us wall at 13-30% VALUBusy (R4/R6). Stage W[n] to LDS
//    with vector loads, read wave-uniform (broadcast, conflict-free).
template <int MODE, bool ATOMIC>
__global__ __launch_bounds__(1024, 1)
void fused_pass(const float* __restrict__ x, const float* __restrict__ W,
                const float* __restrict__ v_in, float* __restrict__ s_out,
                float* __restrict__ rw_out) {
  __shared__ float Wl[2][WN_];               // 2 x 16 KB double-buffered W[n]
  __shared__ float x_lds[CHUNK_ * 8 * 65];   // [rem=(nn*8+i)][b] pad 65 (16.6 KB)
  __shared__ float e_lds[O_ * B_];           // exp storage (8 KB)
  const int tid  = threadIdx.x;
  const int lane = tid & 63;                 // lane == batch b
  const int wave = tid >> 6;                 // 0..15; wave owns o = 2w, 2w+1
  const int n0   = blockIdx.x * CHUNK_;
  const float4* Wg4 = (const float4*)W;      // W[n] = 1024 float4

  // prologue: stage W[n0] + x, one barrier
  float4 w0 = Wg4[(size_t)n0 * 1024 + tid];
  #pragma unroll
  for (int k = 0; k < 4; ++k) {
    int d = k * 1024 + tid;
    int b = d >> 6, rem = d & 63;
    x_lds[rem * 65 + b] = x[b * (N_ * DI_) + n0 * DI_ + rem];
  }
  ((float4*)&Wl[0][0])[tid] = w0;

  float s_r[32];
  #pragma unroll
  for (int q = 0; q < 32; ++q) s_r[q] = 0.0f;

  __syncthreads();

  #pragma unroll 1
  for (int nn = 0; nn < CHUNK_; ++nn) {
    const int n   = n0 + nn;
    const int cur = nn & 1;
    float4 wpre;
    if (nn < CHUNK_ - 1) wpre = Wg4[(size_t)(n + 1) * 1024 + tid];  // prefetch

    float xr[8];
    #pragma unroll
    for (int i = 0; i < 8; ++i) xr[i] = x_lds[(nn * 8 + i) * 65 + lane];

    if (MODE != 0) {
      float pr[2][16];
      float e0 = 0.0f, e1 = 0.0f;
      // ---- A: preds -> regs, logit -> exp -> LDS ----
      #pragma unroll
      for (int oo = 0; oo < 2; ++oo) {
        const int o = wave * 2 + oo;
        const float4* wls = (const float4*)&Wl[cur][o * WROW_];  // wave-uniform
        const float4* vp  = (const float4*)(v_in + (size_t)lane * OP_ + o * P_);
        float acc = 0.0f;
        #pragma unroll
        for (int q = 0; q < 4; ++q) {
          const float4 vq = vp[q];
          #pragma unroll
          for (int pp = 0; pp < 4; ++pp) {
            const int p = q * 4 + pp;
            const float4 wa = wls[p * 2];
            const float4 wb = wls[p * 2 + 1];
            float pv = wa.x * xr[0];
            pv = __builtin_fmaf(wa.y, xr[1], pv);
            pv = __builtin_fmaf(wa.z, xr[2], pv);
            pv = __builtin_fmaf(wa.w, xr[3], pv);
            pv = __builtin_fmaf(wb.x, xr[4], pv);
            pv = __builtin_fmaf(wb.y, xr[5], pv);
            pv = __builtin_fmaf(wb.z, xr[6], pv);
            pv = __builtin_fmaf(wb.w, xr[7], pv);
            pr[oo][p] = pv;
            const float vc = (pp == 0) ? vq.x : (pp == 1) ? vq.y
                           : (pp == 2) ? vq.z : vq.w;
            acc = __builtin_fmaf(pv, vc, acc);
          }
        }
        // no-max softmax: |logit| small analytically; exp safe in fp32
        const float e = __expf(acc);
        if (oo == 0) e0 = e; else e1 = e;
        if (MODE == 2) e_lds[o * B_ + lane] = e;         // individual (rw out)
      }
      if (MODE == 1) e_lds[wave * B_ + lane] = e0 + e1;  // pair partial
      __syncthreads();  // A complete

      float Z = 0.0f;
      if (MODE == 1) {
        #pragma unroll
        for (int w = 0; w < 16; ++w) Z += e_lds[w * B_ + lane];
      } else {
        #pragma unroll
        for (int o = 0; o < O_; ++o) Z += e_lds[o * B_ + lane];
      }
      const float rZ  = __builtin_amdgcn_rcpf(Z);
      const float rw0 = e0 * rZ;
      const float rw1 = e1 * rZ;

      #pragma unroll
      for (int p = 0; p < P_; ++p) {
        s_r[p]      = __builtin_fmaf(rw0, pr[0][p], s_r[p]);
        s_r[16 + p] = __builtin_fmaf(rw1, pr[1][p], s_r[16 + p]);
      }

      if (MODE == 2 && wave == nn) {
        float* rp = rw_out + ((size_t)lane * N_ + n) * O_;
        #pragma unroll
        for (int o4 = 0; o4 < 8; ++o4) {
          float4 t;
          t.x = e_lds[(o4 * 4 + 0) * B_ + lane] * rZ;
          t.y = e_lds[(o4 * 4 + 1) * B_ + lane] * rZ;
          t.z = e_lds[(o4 * 4 + 2) * B_ + lane] * rZ;
          t.w = e_lds[(o4 * 4 + 3) * B_ + lane] * rZ;
          ((float4*)rp)[o4] = t;
        }
      }
    } else {
      // ---- MODE0: uniform rw (scale folded downstream) ----
      #pragma unroll
      for (int oo = 0; oo < 2; ++oo) {
        const int o = wave * 2 + oo;
        const float4* wls = (const float4*)&Wl[cur][o * WROW_];
        #pragma unroll
        for (int q = 0; q < 4; ++q) {
          #pragma unroll
          for (int pp = 0; pp < 4; ++pp) {
            const int p = q * 4 + pp;
            const float4 wa = wls[p * 2];
            const float4 wb = wls[p * 2 + 1];
            float pv = wa.x * xr[0];
            pv = __builtin_fmaf(wa.y, xr[1], pv);
            pv = __builtin_fmaf(wa.z, xr[2], pv);
            pv = __builtin_fmaf(wa.w, xr[3], pv);
            pv = __builtin_fmaf(wb.x, xr[4], pv);
            pv = __builtin_fmaf(wb.y, xr[5], pv);
            pv = __builtin_fmaf(wb.z, xr[6], pv);
            pv = __builtin_fmaf(wb.w, xr[7], pv);
            s_r[oo * 16 + p] += pv;
          }
        }
      }
    }

    if (nn < CHUNK_ - 1) ((float4*)&Wl[cur ^ 1][0])[tid] = wpre;  // stage next W
    __syncthreads();  // next-W visible; e_lds free for reuse
  }

  // epilogue: block partial (layout [blk][q=o*16+p][b]) or atomic fallback
  if (ATOMIC) {
    #pragma unroll
    for (int oo = 0; oo < 2; ++oo) {
      float* sp = s_out + (size_t)((wave * 2 + oo) * P_) * B_ + lane;
      #pragma unroll
      for (int p = 0; p < P_; ++p) atomicAdd(&sp[p * B_], s_r[oo * 16 + p]);
    }
  } else {
    #pragma unroll
    for (int oo = 0; oo < 2; ++oo) {
      float* sp = s_out + (size_t)blockIdx.x * M_ +
                  (size_t)((wave * 2 + oo) * P_) * B_ + lane;
      #pragma unroll
      for (int p = 0; p < P_; ++p) sp[p * B_] = s_r[oo * 16 + p];
    }
  }
}

// stage-1 reduction: P[K][M_] -> P2[16][M_]; grid 16 groups x 16 m-chunks.
__global__ __launch_bounds__(1024)
void reduce1(const float* __restrict__ spart, float* __restrict__ p2, int K) {
  const int g  = blockIdx.x >> 4;
  const int mc = blockIdx.x & 15;
  const int kpg = K >> 4;
  const int m0 = mc * 2048 + threadIdx.x;
  float a0 = 0.0f, a1 = 0.0f;
  const float* p = spart + (size_t)(g * kpg) * M_;
  for (int k = 0; k < kpg; ++k) {
    a0 += p[(size_t)k * M_ + m0];
    a1 += p[(size_t)k * M_ + m0 + 1024];
  }
  p2[(size_t)g * M_ + m0]        = a0;
  p2[(size_t)g * M_ + m0 + 1024] = a1;
}

// sum ngroups (stride M_) + squash; optionally add v_add; optionally zero a buffer.
__global__ __launch_bounds__(1024)
void v_kernel(const float* __restrict__ src, int ngroups, float scale,
              const float* __restrict__ v_add, float* __restrict__ v_out,
              float* __restrict__ zero_buf) {
  __shared__ float sq[P_ * 64];
  const int t = threadIdx.x;
  const int b = t & 63;
  const int p = t >> 6;
  const int o = blockIdx.x;
  const int q = o * P_ + p;
  float acc = 0.0f;
  for (int g = 0; g < ngroups; ++g) acc += src[(size_t)g * M_ + q * 64 + b];
  acc *= scale;
  sq[p * 64 + b] = acc * acc;
  if (zero_buf) zero_buf[blockIdx.x * 1024 + t] = 0.0f;
  __syncthreads();
  float s2 = 0.0f;
  #pragma unroll
  for (int pp = 0; pp < P_; ++pp) s2 += sq[pp * 64 + b];
  float sc = (s2 / (1.0f + s2)) / sqrtf(s2 + 1e-7f);
  float v = acc * sc;
  const int idx = b * OP_ + q;   // v layout [b][o][p]
  v_out[idx] = v + (v_add ? v_add[idx] : 0.0f);
}

extern "C" void kernel_launch(void* const* d_in, const int* in_sizes, int n_in,
                              void* d_out, int out_size, void* d_ws, size_t ws_size,
                              hipStream_t stream) {
  (void)in_sizes; (void)n_in; (void)out_size;
  const float* x = (const float*)d_in[0];
  const float* W = (const float*)d_in[1];
  float* out_v  = (float*)d_out;                       // [64][32][16]
  float* out_rw = out_v + (size_t)B_ * O_ * P_;        // [64][2048][32]
  float* vws   = (float*)d_ws;                         // v0
  float* vsum  = vws + M_;                             // v0+v1
  float* p2    = vsum + M_;                            // 16 * M_
  float* spart = p2 + 16 * M_;                         // NBLK_ * M_

  const size_t need = (size_t)(2 * M_ + 16 * M_ + (size_t)NBLK_ * M_) * 4;

  dim3 gF(NBLK_), bF(1024), gV(O_), bV(1024), gR(256);
  if (ws_size >= need) {
    fused_pass<0, false><<<gF, bF, 0, stream>>>(x, W, nullptr, spart, nullptr);
    reduce1<<<gR, bF, 0, stream>>>(spart, p2, NBLK_);
    v_kernel<<<gV, bV, 0, stream>>>(p2, 16, 1.0f / 32.0f, nullptr, vws, nullptr);
    fused_pass<1, false><<<gF, bF, 0, stream>>>(x, W, vws, spart, nullptr);
    reduce1<<<gR, bF, 0, stream>>>(spart, p2, NBLK_);
    v_kernel<<<gV, bV, 0, stream>>>(p2, 16, 1.0f, vws, vsum, nullptr);
    fused_pass<2, false><<<gF, bF, 0, stream>>>(x, W, vsum, spart, out_rw);
    reduce1<<<gR, bF, 0, stream>>>(spart, p2, NBLK_);
    v_kernel<<<gV, bV, 0, stream>>>(p2, 16, 1.0f, nullptr, out_v, nullptr);
  } else {
    // atomic fallback for small ws
    float* sAb = p2;
    float* sBb = sAb + M_;
    hipMemsetAsync(sAb, 0, (size_t)M_ * sizeof(float), stream);
    fused_pass<0, true><<<gF, bF, 0, stream>>>(x, W, nullptr, sAb, nullptr);
    v_kernel<<<gV, bV, 0, stream>>>(sAb, 1, 1.0f / 32.0f, nullptr, vws, sBb);
    fused_pass<1, true><<<gF, bF, 0, stream>>>(x, W, vws, sBb, nullptr);
    v_kernel<<<gV, bV, 0, stream>>>(sBb, 1, 1.0f, vws, vsum, sAb);
    fused_pass<2, true><<<gF, bF, 0, stream>>>(x, W, vsum, sAb, out_rw);
    v_kernel<<<gV, bV, 0, stream>>>(sAb, 1, 1.0f, nullptr, out_v, nullptr);
  }
}